// Round 5
// baseline (485.295 us; speedup 1.0000x reference)
//
#include <hip/hip_runtime.h>

// SAGE layer. Structure:
// 1. Message linear commutes with segment-mean -> aggregate RAW [nf[src]||ef]
//    per dst node, apply W_msg once per node (13.1 GFLOP -> 0.8 GFLOP).
// 2. CSR-by-dst built on device (histogram -> hierarchical scan -> scatter of
//    packed int2{eid,src}); zero f32 atomics.
// 3. gather_node FUSES aggregation + both GEMVs: per-node sums go through LDS
//    instead of a 51MB agg round-trip through HBM. 4 edges in flight per wave
//    (16 lanes x float4 per 256B row), 2x unrolled.
// Note: ~250us of dur_us is harness fixed overhead (819MB ws poison fill +
// d_in restores show as fillBufferAligned at ~122us in rocprof).

// Packed-transpose: T[(f>>2)*256 + o*4 + (f&3)] = W[o*128+f], so thread o can
// read its 4 weights of an f-quad as one float4 (coalesced 1KB per wave).
__global__ void transpose_w(const float* __restrict__ Wm, const float* __restrict__ Wa,
                            float* __restrict__ WmT, float* __restrict__ WaT) {
    int idx = blockIdx.x * blockDim.x + threadIdx.x;   // 0..16383
    if (idx >= 2 * 64 * 128) return;
    const float* S = (idx < 8192) ? Wm : Wa;
    float*       T = (idx < 8192) ? WmT : WaT;
    int r = idx & 8191;
    int o = r >> 7;     // output channel
    int f = r & 127;    // input feature
    T[(f >> 2) * 256 + (o << 2) + (f & 3)] = S[o * 128 + f];
}

// --- CSR build ---------------------------------------------------------------

__global__ void histogram(const int* __restrict__ dst, int* __restrict__ cnt, int E) {
    int e = blockIdx.x * blockDim.x + threadIdx.x;
    if (e >= E) return;
    atomicAdd(&cnt[dst[e]], 1);
}

__global__ __launch_bounds__(256) void scan_local(
    const int* __restrict__ cnt, int* __restrict__ excl, int* __restrict__ bsums, int N) {
    __shared__ int s[256];
    int t = threadIdx.x;
    int i = blockIdx.x * 256 + t;
    int v = (i < N) ? cnt[i] : 0;
    s[t] = v;
    __syncthreads();
    #pragma unroll
    for (int off = 1; off < 256; off <<= 1) {
        int tmp = (t >= off) ? s[t - off] : 0;
        __syncthreads();
        s[t] += tmp;
        __syncthreads();
    }
    if (i < N) excl[i] = s[t] - v;          // local exclusive
    if (t == 255) bsums[blockIdx.x] = s[255];
}

__global__ __launch_bounds__(256) void scan_bsums(int* __restrict__ bsums, int B) {
    __shared__ int s[256];
    int t = threadIdx.x;
    int v = (t < B) ? bsums[t] : 0;
    s[t] = v;
    __syncthreads();
    #pragma unroll
    for (int off = 1; off < 256; off <<= 1) {
        int tmp = (t >= off) ? s[t - off] : 0;
        __syncthreads();
        s[t] += tmp;
        __syncthreads();
    }
    if (t < B) bsums[t] = s[t] - v;         // exclusive block offsets
}

__global__ __launch_bounds__(256) void scan_add(
    int* __restrict__ offs, int* __restrict__ cursor,
    const int* __restrict__ bsums, int N, int E) {
    int i = blockIdx.x * 256 + threadIdx.x;
    if (i < N) {
        int v = offs[i] + bsums[blockIdx.x];
        offs[i]   = v;
        cursor[i] = v;
    }
    if (i == 0) offs[N] = E;
}

__global__ void scatter_eids(const int* __restrict__ dst, const int* __restrict__ src,
                             int* __restrict__ cursor, int2* __restrict__ epk, int E) {
    int e = blockIdx.x * blockDim.x + threadIdx.x;
    if (e >= E) return;
    int pos = atomicAdd(&cursor[dst[e]], 1);
    epk[pos] = make_int2(e, src[e]);        // one 8B scatter (was two 4B)
}

// --- Fused aggregate + node update: 4 nodes per block, one wave each ---------
__device__ inline float4 xor_add(float4 v, int m) {
    v.x += __shfl_xor(v.x, m);
    v.y += __shfl_xor(v.y, m);
    v.z += __shfl_xor(v.z, m);
    v.w += __shfl_xor(v.w, m);
    return v;
}
__device__ inline void acc4(float4& a, const float4 b) {
    a.x += b.x; a.y += b.y; a.z += b.z; a.w += b.w;
}

__global__ __launch_bounds__(256) void gather_node(
    const float4* __restrict__ nf4, const float4* __restrict__ ef4,
    const int2* __restrict__ epk,   const int* __restrict__ offs,
    const float* __restrict__ nfeats,
    const float* __restrict__ WmT,  const float* __restrict__ bm,
    const float* __restrict__ WaT,  const float* __restrict__ ba,
    float* __restrict__ out, int N) {
    __shared__ float s_x[4][128];   // mean of [nf_sum || ef_sum]
    __shared__ float s_z[4][128];   // [nfeats || h_neigh]
    __shared__ float s_deg[4];
    int wave = threadIdx.x >> 6;
    int lane = threadIdx.x & 63;
    int n = blockIdx.x * 4 + wave;
    bool active = (n < N);
    int g = lane >> 4;              // edge group 0..3
    int l = lane & 15;              // float4 slot within a 256B row

    // self feature -> LDS (overlaps with edge loop)
    s_z[wave][lane] = active ? nfeats[(size_t)n * 64 + lane] : 0.f;

    int start = 0, end = 0;
    if (active) { start = offs[n]; end = offs[n + 1]; }
    float4 anf = {0.f, 0.f, 0.f, 0.f};
    float4 aef = {0.f, 0.f, 0.f, 0.f};
    for (int base = start; base < end; base += 64) {
        int m = end - base; if (m > 64) m = 64;
        int2 p = make_int2(0, 0);
        if (lane < m) p = epk[base + lane];
        int jmax = (m + 3) >> 2;
        int j = 0;
        for (; j + 2 <= jmax; j += 2) {           // 2 edges per group in flight
            int k0 = (j << 2) + g, k1 = k0 + 4;
            int e0 = __shfl(p.x, k0), s0 = __shfl(p.y, k0);
            int e1 = __shfl(p.x, k1), s1 = __shfl(p.y, k1);
            float4 a0 = {0,0,0,0}, b0 = {0,0,0,0}, a1 = {0,0,0,0}, b1 = {0,0,0,0};
            if (k0 < m) { a0 = nf4[(size_t)s0 * 16 + l]; b0 = ef4[(size_t)e0 * 16 + l]; }
            if (k1 < m) { a1 = nf4[(size_t)s1 * 16 + l]; b1 = ef4[(size_t)e1 * 16 + l]; }
            acc4(anf, a0); acc4(aef, b0);
            acc4(anf, a1); acc4(aef, b1);
        }
        for (; j < jmax; ++j) {
            int k = (j << 2) + g;
            int eid = __shfl(p.x, k);
            int s   = __shfl(p.y, k);
            if (k < m) {
                acc4(anf, nf4[(size_t)s   * 16 + l]);
                acc4(aef, ef4[(size_t)eid * 16 + l]);
            }
        }
    }
    // cross-group reduce: lanes {l, l+16, l+32, l+48} hold partials of slot l
    anf = xor_add(anf, 16); anf = xor_add(anf, 32);
    aef = xor_add(aef, 16); aef = xor_add(aef, 32);
    float dg  = (float)(end - start);
    float inv = dg > 0.f ? 1.0f / dg : 0.0f;
    if (g == 0) {
        float4 v = {anf.x * inv, anf.y * inv, anf.z * inv, anf.w * inv};
        *(float4*)&s_x[wave][l * 4] = v;
    } else if (g == 1) {
        float4 v = {aef.x * inv, aef.y * inv, aef.z * inv, aef.w * inv};
        *(float4*)&s_x[wave][64 + l * 4] = v;
    }
    if (lane == 0) s_deg[wave] = dg;
    __syncthreads();

    // Phase 2: thread (wave, lane=o) computes output channel o of node n.
    int o = lane;
    const float4* Wm4 = (const float4*)WmT;
    float acc = 0.f;
    #pragma unroll 8
    for (int f4 = 0; f4 < 32; ++f4) {
        float4 w  = Wm4[f4 * 64 + o];
        float4 xv = *(const float4*)&s_x[wave][f4 * 4];
        acc += xv.x * w.x + xv.y * w.y + xv.z * w.z + xv.w * w.w;
    }
    float hn = (s_deg[wave] > 0.f) ? acc + bm[o] : 0.f;   // isolated -> 0
    s_z[wave][64 + o] = hn;
    __syncthreads();

    const float4* Wa4 = (const float4*)WaT;
    float acc2 = 0.f;
    #pragma unroll 8
    for (int f4 = 0; f4 < 32; ++f4) {
        float4 w  = Wa4[f4 * 64 + o];
        float4 zv = *(const float4*)&s_z[wave][f4 * 4];
        acc2 += zv.x * w.x + zv.y * w.y + zv.z * w.z + zv.w * w.w;
    }
    if (active) {
        float h = acc2 + ba[o];
        out[(size_t)n * 64 + o] = h > 0.f ? h : 0.f;
    }
}

extern "C" void kernel_launch(void* const* d_in, const int* in_sizes, int n_in,
                              void* d_out, int out_size, void* d_ws, size_t ws_size,
                              hipStream_t stream) {
    const float* nfeats = (const float*)d_in[0];   // [N,1,64]
    const float* efeats = (const float*)d_in[1];   // [E,1,64]
    const int*   src    = (const int*)d_in[2];     // [E]
    const int*   dst    = (const int*)d_in[3];     // [E]
    const float* Wm     = (const float*)d_in[4];   // [64,128]
    const float* bm     = (const float*)d_in[5];   // [64]
    const float* Wa     = (const float*)d_in[6];   // [64,128]
    const float* ba     = (const float*)d_in[7];   // [64]
    float* out = (float*)d_out;                    // [N,1,64] fp32

    const int N = in_sizes[0] / 64;
    const int E = in_sizes[2];
    const int NB = (N + 255) / 256;                // scan blocks (196 <= 256)

    // workspace layout:
    float* WmT    = (float*)d_ws;                  // 8192 f32 (packed-transposed)
    float* WaT    = WmT + 8192;                    // 8192 f32
    int*   cnt    = (int*)(WaT + 8192);            // N i32
    int*   offs   = cnt + N;                       // N+1 i32
    int*   cursor = offs + N + 1;                  // N i32
    int*   bsums  = cursor + N;                    // 256 i32
    int2*  epk    = (int2*)(((uintptr_t)(bsums + 256) + 15) & ~(uintptr_t)15); // E int2

    (void)hipMemsetAsync(cnt, 0, (size_t)N * sizeof(int), stream);

    transpose_w<<<64, 256, 0, stream>>>(Wm, Wa, WmT, WaT);
    histogram<<<(E + 255) / 256, 256, 0, stream>>>(dst, cnt, E);
    scan_local<<<NB, 256, 0, stream>>>(cnt, offs, bsums, N);
    scan_bsums<<<1, 256, 0, stream>>>(bsums, NB);
    scan_add<<<NB, 256, 0, stream>>>(offs, cursor, bsums, N, E);
    scatter_eids<<<(E + 255) / 256, 256, 0, stream>>>(dst, src, cursor, epk, E);
    gather_node<<<(N + 3) / 4, 256, 0, stream>>>(
        (const float4*)nfeats, (const float4*)efeats, epk, offs,
        nfeats, WmT, bm, WaT, ba, out, N);
}